// Round 4
// baseline (110.477 us; speedup 1.0000x reference)
//
#include <hip/hip_runtime.h>
#include <math.h>

// Additive attention, MI355X. B=4, Q=K=1024, QSIZE=KSIZE=256, H=32, VDIM=256.
//
// Math: tanh(fq+fk) = 1 - 2/(1 + e^{2fq} e^{2fk}); precompute eq=e^{2fq}, ek=e^{2fk}.
// score = const - 2*sum_h w_h/u_h, u_h = 1 + eq_h ek_h; const cancels in softmax.
// Rational 2-level combine -> 1 rcp per 4 h. Masked k skipped; normalization deferred.
//
// R12: proj = R9 exact (2-row W-reuse, 512 blocks; R11's 4-row/256-block cut
// occupancy to 4 waves/CU and regressed -- grid-shrink trap, twice confirmed).
// attn: TQ=16 with 2-way K-SPLIT across blocks. Grid stays 512 balanced blocks
// (= R9's occupancy & per-batch averaging), but each values row now serves 16
// q-rows -> values L2 traffic 512 MB -> 256 MB (the measured-dominant attn cost;
// BMM is L2-BW-bound: demand ~128 B/cyc/CU vs ~56 supply, R8 pk_fma null).
// Blocks write unnormalized partials num[b][q][kh][256] (8 MB ws) + den; tiny
// combine kernel does (num0+num1)/(den0+den1) (~12 MB traffic ~= 2 us).

#define NB 4
#define NQ 1024
#define NK 1024
#define DQK 256
#define NH 32
#define NV 256
#define TQ 16   // q-rows per attn block
#define BLK 512 // attn block size (8 waves)

typedef __attribute__((ext_vector_type(2))) float f32x2;

__device__ __forceinline__ float fast_rcp(float x) { return __builtin_amdgcn_rcpf(x); }

// ---------------------------------------------------------------------------
// Kernel 1: projections + exp(2x). Thread = (row-PAIR, 4-h group, quarter of dims).
// 4096 row-pairs * 8 hgroups * 4 quarters = 131072 threads = 512 blocks. (R9 exact)
__global__ __launch_bounds__(256) void proj_kernel(
    const float* __restrict__ queries, const float* __restrict__ keys,
    const float* __restrict__ W_q, const float* __restrict__ b_q,
    const float* __restrict__ W_k, const float* __restrict__ b_k,
    float* __restrict__ eq, float* __restrict__ ek)
{
    const int tid     = blockIdx.x * 256 + threadIdx.x;
    const int g       = tid >> 5;            // row-pair 0..4095
    const int sub     = tid & 31;
    const int h4      = (sub & 7) * 4;       // h-group
    const int quarter = sub >> 3;            // 0..3 -> dims quarter*64..+63

    const int row0 = g * 2;
    const float* src; const float* W; const float* bias; float* dst; int r;
    if (row0 < NB * NQ) { r = row0;           src = queries + (size_t)r * DQK; W = W_q; bias = b_q; dst = eq; }
    else                { r = row0 - NB * NQ; src = keys    + (size_t)r * DQK; W = W_k; bias = b_k; dst = ek; }

    f32x2 a01A = {0.f, 0.f}, a23A = {0.f, 0.f};   // row r
    f32x2 a01B = {0.f, 0.f}, a23B = {0.f, 0.f};   // row r+1
    if (quarter == 0) {
        float4 bv4 = *(const float4*)(bias + h4);
        a01A = (f32x2){bv4.x, bv4.y}; a23A = (f32x2){bv4.z, bv4.w};
        a01B = a01A; a23B = a23A;
    }
    const float* srcA = src;
    const float* srcB = src + DQK;
    const int d0 = quarter * 64;
    #pragma unroll 4
    for (int i = d0; i < d0 + 64; i += 4) {
        float4 sA = *(const float4*)(srcA + i);
        float4 sB = *(const float4*)(srcB + i);
        float4 w0 = *(const float4*)(W + (size_t)(i + 0) * NH + h4);
        float4 w1 = *(const float4*)(W + (size_t)(i + 1) * NH + h4);
        float4 w2 = *(const float4*)(W + (size_t)(i + 2) * NH + h4);
        float4 w3 = *(const float4*)(W + (size_t)(i + 3) * NH + h4);
#define PSTEP2(SA, SB, WR) \
        a01A = __builtin_elementwise_fma((f32x2){SA, SA}, (f32x2){WR.x, WR.y}, a01A); \
        a23A = __builtin_elementwise_fma((f32x2){SA, SA}, (f32x2){WR.z, WR.w}, a23A); \
        a01B = __builtin_elementwise_fma((f32x2){SB, SB}, (f32x2){WR.x, WR.y}, a01B); \
        a23B = __builtin_elementwise_fma((f32x2){SB, SB}, (f32x2){WR.z, WR.w}, a23B);
        PSTEP2(sA.x, sB.x, w0) PSTEP2(sA.y, sB.y, w1)
        PSTEP2(sA.z, sB.z, w2) PSTEP2(sA.w, sB.w, w3)
#undef PSTEP2
    }
    float a0A = a01A.x, a1A = a01A.y, a2A = a23A.x, a3A = a23A.y;
    float a0B = a01B.x, a1B = a01B.y, a2B = a23B.x, a3B = a23B.y;
    a0A += __shfl_xor(a0A, 8, 64);  a1A += __shfl_xor(a1A, 8, 64);
    a2A += __shfl_xor(a2A, 8, 64);  a3A += __shfl_xor(a3A, 8, 64);
    a0B += __shfl_xor(a0B, 8, 64);  a1B += __shfl_xor(a1B, 8, 64);
    a2B += __shfl_xor(a2B, 8, 64);  a3B += __shfl_xor(a3B, 8, 64);
    a0A += __shfl_xor(a0A, 16, 64); a1A += __shfl_xor(a1A, 16, 64);
    a2A += __shfl_xor(a2A, 16, 64); a3A += __shfl_xor(a3A, 16, 64);
    a0B += __shfl_xor(a0B, 16, 64); a1B += __shfl_xor(a1B, 16, 64);
    a2B += __shfl_xor(a2B, 16, 64); a3B += __shfl_xor(a3B, 16, 64);
    if (quarter == 0) {
        float4 oA, oB;
        oA.x = __expf(2.f * a0A); oA.y = __expf(2.f * a1A);
        oA.z = __expf(2.f * a2A); oA.w = __expf(2.f * a3A);
        oB.x = __expf(2.f * a0B); oB.y = __expf(2.f * a1B);
        oB.z = __expf(2.f * a2B); oB.w = __expf(2.f * a3B);
        *(float4*)(dst + (size_t)r * NH + h4)       = oA;
        *(float4*)(dst + (size_t)(r + 1) * NH + h4) = oB;
    }
}

// ---------------------------------------------------------------------------
// Kernel 2: scores + exp + partial (unnormalized) weighted sum over a K-HALF.
// Block = (b, q-group of 16, k-half). grid = 4*64*2 = 512 blocks of 512 threads.
// Wave w owns a k-subrange for BOTH score and BMM phases (no barrier between).
// Writes num[b][q][kh][256] and den[b][q][kh] partials to workspace.
__global__ __launch_bounds__(BLK, 4) void attn_kernel(
    const float* __restrict__ eq, const float* __restrict__ ek,
    const float* __restrict__ values, const int* __restrict__ valid_lens,
    const float* __restrict__ w_v, float* __restrict__ num, float* __restrict__ den)
{
    // 64 KB reduction buffer [4 regions][TQ][256]; first 32 KB doubles as
    // s_w[512][TQ] (unnormalized exp-weights, k local to this half).
    __shared__ float sbuf[4 * TQ * 256];
    __shared__ float s_part[8][TQ];
    float (*s_w)[TQ] = (float (*)[TQ])sbuf;

    const int t      = threadIdx.x;
    const int b      = blockIdx.x >> 7;
    const int qg     = (blockIdx.x >> 1) & 63;
    const int kh     = blockIdx.x & 1;
    const int q0     = qg * TQ;
    const int nvalid = valid_lens[b];           // [1, 1024]
    const int wave   = t >> 6;
    const int lane   = t & 63;
    const int qi     = lane & 15;
    const int kk     = lane >> 4;               // 0..3

    const int half_len = (nvalid + 1) >> 1;
    const int k_lo  = kh * half_len;
    const int k_hi  = min(nvalid, k_lo + half_len);
    const int count = k_hi - k_lo;              // may be 0 (nvalid==1, kh==1)

    const int kpw  = (count + 7) >> 3;          // k's per wave (8 waves)
    const int kbeg = k_lo + wave * kpw;
    const int kend = min(k_hi, kbeg + kpw);

    float wv[NH];
    #pragma unroll
    for (int h = 0; h < NH; h += 4) {
        float4 w4 = *(const float4*)(w_v + h);
        wv[h] = w4.x; wv[h+1] = w4.y; wv[h+2] = w4.z; wv[h+3] = w4.w;
    }
    float eqr[NH];
    const float* eqp = eq + (size_t)(b * NQ + q0 + qi) * NH;
    #pragma unroll
    for (int h = 0; h < NH; h += 4) {
        float4 e4 = *(const float4*)(eqp + h);
        eqr[h] = e4.x; eqr[h+1] = e4.y; eqr[h+2] = e4.z; eqr[h+3] = e4.w;
    }

    // ---- scores + exp -> unnormalized weights into this wave's s_w region
    const float* ekbase = ek + (size_t)b * NK * NH;
    float ssum = 0.f;
    for (int k0 = kbeg; k0 < kend; k0 += 4) {
        const int k = k0 + kk;
        if (k < kend) {
            const float* ekp = ekbase + (size_t)k * NH;
            float acc = 0.f;
            #pragma unroll
            for (int h = 0; h < NH; h += 4) {
                float4 e4 = *(const float4*)(ekp + h);
                float u0 = fmaf(eqr[h+0], e4.x, 1.f);
                float u1 = fmaf(eqr[h+1], e4.y, 1.f);
                float u2 = fmaf(eqr[h+2], e4.z, 1.f);
                float u3 = fmaf(eqr[h+3], e4.w, 1.f);
                float d01 = u0 * u1, d23 = u2 * u3;
                float n01 = fmaf(wv[h+0], u1, wv[h+1] * u0);
                float n23 = fmaf(wv[h+2], u3, wv[h+3] * u2);
                float d   = fminf(d01 * d23, 1e38f);   // inf guard
                float n   = fmaf(n01, d23, n23 * d01);
                acc = fmaf(n, fast_rcp(d), acc);
            }
            float e = __expf(-2.f * acc);
            s_w[k - k_lo][qi] = e;   // 64 consecutive floats/pass -> 2-way alias
            ssum += e;
        }
    }

    // per-wave softmax denominator partial (reduce over kk = lane bits 4,5)
    ssum += __shfl_xor(ssum, 16, 64);
    ssum += __shfl_xor(ssum, 32, 64);
    if (lane < TQ) s_part[wave][lane] = ssum;

    // ---- bmm over the same k-range (weights written by THIS wave: no barrier)
    f32x2 al[TQ], ah[TQ];
    #pragma unroll
    for (int j = 0; j < TQ; j++) { al[j] = (f32x2){0.f, 0.f}; ah[j] = (f32x2){0.f, 0.f}; }
    const float* vbase = values + (size_t)b * NK * NV + 4 * lane;

    #pragma unroll 2
    for (int k = kbeg; k < kend; k++) {
        float4 v  = *(const float4*)(vbase + (size_t)k * NV);
        f32x2 vl = {v.x, v.y}, vh = {v.z, v.w};
        const int kl = k - k_lo;
        float4 w0 = *(const float4*)(&s_w[kl][0]);   // wave-uniform broadcast
        float4 w1 = *(const float4*)(&s_w[kl][4]);
        float4 w2 = *(const float4*)(&s_w[kl][8]);
        float4 w3 = *(const float4*)(&s_w[kl][12]);
        const float wq[TQ] = {w0.x,w0.y,w0.z,w0.w, w1.x,w1.y,w1.z,w1.w,
                              w2.x,w2.y,w2.z,w2.w, w3.x,w3.y,w3.z,w3.w};
        #pragma unroll
        for (int j = 0; j < TQ; j++) {
            al[j] = __builtin_elementwise_fma((f32x2){wq[j], wq[j]}, vl, al[j]);
            ah[j] = __builtin_elementwise_fma((f32x2){wq[j], wq[j]}, vh, ah[j]);
        }
    }

    __syncthreads();                 // everyone done with s_w as weights
    float4* p = (float4*)(sbuf + (size_t)((wave & 3) * TQ) * 256) + lane;
    if (wave < 4) {                  // round A: waves 0..3 write their partials
        #pragma unroll
        for (int j = 0; j < TQ; j++)
            p[j * 64] = (float4){al[j].x, al[j].y, ah[j].x, ah[j].y};
    }
    __syncthreads();
    if (wave >= 4) {                 // round B: waves 4..7 accumulate in place
        #pragma unroll
        for (int j = 0; j < TQ; j++) {
            float4 x4 = p[j * 64];
            x4.x += al[j].x; x4.y += al[j].y; x4.z += ah[j].x; x4.w += ah[j].y;
            p[j * 64] = x4;
        }
    }
    __syncthreads();

    // ---- final reduction over 4 regions -> partial num/den to workspace.
    const int v  = t & 255;
    const int qh = (t >> 8) * 8;     // 0 or 8
    #pragma unroll
    for (int jj = 0; jj < 8; jj++) {
        const int q = qh + jj;
        float r = sbuf[(0*TQ + q) * 256 + v] + sbuf[(1*TQ + q) * 256 + v]
                + sbuf[(2*TQ + q) * 256 + v] + sbuf[(3*TQ + q) * 256 + v];
        num[(((size_t)(b * NQ + q0 + q) * 2) + kh) * NV + v] = r;
    }
    if (t < TQ) {
        float tot = 0.f;
        #pragma unroll
        for (int w = 0; w < 8; w++) tot += s_part[w][t];
        den[((size_t)(b * NQ + q0 + t) * 2) + kh] = tot;
    }
}

// ---------------------------------------------------------------------------
// Kernel 3: combine the two k-half partials: out = (num0+num1)/(den0+den1).
// 262144 float4 cells; 1024 blocks * 256 threads, one float4 each.
__global__ __launch_bounds__(256) void combine_kernel(
    const float* __restrict__ num, const float* __restrict__ den,
    float* __restrict__ out)
{
    const int g   = blockIdx.x * 256 + threadIdx.x;   // 0..262143
    const int row = g >> 6;                           // b*NQ + q
    const int v4  = g & 63;
    const float4* n4 = (const float4*)num;
    float d = den[row * 2 + 0] + den[row * 2 + 1];
    float4 a = n4[(size_t)(row * 2 + 0) * 64 + v4];
    float4 c = n4[(size_t)(row * 2 + 1) * 64 + v4];
    float rs = fast_rcp(d);
    float4 o = {(a.x + c.x) * rs, (a.y + c.y) * rs, (a.z + c.z) * rs, (a.w + c.w) * rs};
    ((float4*)out)[(size_t)row * 64 + v4] = o;
}

// ---------------------------------------------------------------------------
extern "C" void kernel_launch(void* const* d_in, const int* in_sizes, int n_in,
                              void* d_out, int out_size, void* d_ws, size_t ws_size,
                              hipStream_t stream) {
    (void)in_sizes; (void)n_in; (void)out_size; (void)ws_size;
    const float* keys       = (const float*)d_in[0];
    const float* queries    = (const float*)d_in[1];
    const float* values     = (const float*)d_in[2];
    const int*   valid_lens = (const int*)d_in[3];
    const float* W_q        = (const float*)d_in[4];
    const float* b_q        = (const float*)d_in[5];
    const float* W_k        = (const float*)d_in[6];
    const float* b_k        = (const float*)d_in[7];
    const float* w_v        = (const float*)d_in[8];
    // d_in[9] = b_v: cancels in softmax.
    float* out = (float*)d_out;

    float* eq  = (float*)d_ws;                       // B*Q*32 floats   (512 KB)
    float* ek  = eq + (size_t)NB * NQ * NH;          // B*K*32 floats   (512 KB)
    float* num = ek + (size_t)NB * NK * NH;          // B*Q*2*256 floats (8 MB)
    float* den = num + (size_t)NB * NQ * 2 * NV;     // B*Q*2 floats    (32 KB)

    proj_kernel<<<dim3(512), dim3(256), 0, stream>>>(queries, keys, W_q, b_q, W_k, b_k, eq, ek);
    attn_kernel<<<dim3(NB * (NQ / TQ) * 2), dim3(BLK), 0, stream>>>(eq, ek, values, valid_lens, w_v, num, den);
    combine_kernel<<<dim3(1024), dim3(256), 0, stream>>>(num, den, out);
}

// Round 5
// 107.302 us; speedup vs baseline: 1.0296x; 1.0296x over previous
//
#include <hip/hip_runtime.h>
#include <math.h>

// Additive attention, MI355X. B=4, Q=K=1024, QSIZE=KSIZE=256, H=32, VDIM=256.
//
// Math: tanh(fq+fk) = 1 - 2/(1 + e^{2fq} e^{2fk}); precompute eq=e^{2fq}, ek=e^{2fk}.
// score = const - 2*sum_h w_h/u_h, u_h = 1 + eq_h ek_h; const cancels in softmax.
// Rational 2-level combine -> 1 rcp per 4 h. Masked k skipped; normalization deferred.
//
// R13: REVERT to R9 exactly (measured best, 106.66 us). Post-mortems:
//  - R10 (TQ=16, 256 blocks): +9us  -- 1 block/CU exposes per-batch imbalance.
//  - R11 (proj 4-row, 256 blocks): +2.4us -- occupancy collapse, same trap.
//  - R12 (TQ=16 + k-split + combine): +3.8us -- values-L2-BW theory REFUTED
//    (halved values traffic returned ~0; combine overhead undamped).
// Conclusion: attn is issue+imbalance bound near its structural floor;
// every capture mechanism tried (2 sessions, 7 attempts) cost more than it
// recovered. R9 config: proj 2-row W-reuse @512 blocks; attn TQ=8 @512 blocks,
// contiguous batch mapping, wave-owns-k-range, deferred normalization.

#define NB 4
#define NQ 1024
#define NK 1024
#define DQK 256
#define NH 32
#define NV 256
#define TQ 8    // q-rows per attn block
#define BLK 512 // attn block size (8 waves)

typedef __attribute__((ext_vector_type(2))) float f32x2;

__device__ __forceinline__ float fast_rcp(float x) { return __builtin_amdgcn_rcpf(x); }

// ---------------------------------------------------------------------------
// Kernel 1: projections + exp(2x). Thread = (row-PAIR, 4-h group, quarter of dims).
// 4096 row-pairs * 8 hgroups * 4 quarters = 131072 threads = 512 blocks.
// Rows 2g, 2g+1 share the W loads (register reuse); q/k split at 4096 is even,
// so both rows of a pair are always on the same side.
__global__ __launch_bounds__(256) void proj_kernel(
    const float* __restrict__ queries, const float* __restrict__ keys,
    const float* __restrict__ W_q, const float* __restrict__ b_q,
    const float* __restrict__ W_k, const float* __restrict__ b_k,
    float* __restrict__ eq, float* __restrict__ ek)
{
    const int tid     = blockIdx.x * 256 + threadIdx.x;
    const int g       = tid >> 5;            // row-pair 0..4095
    const int sub     = tid & 31;
    const int h4      = (sub & 7) * 4;       // h-group
    const int quarter = sub >> 3;            // 0..3 -> dims quarter*64..+63

    const int row0 = g * 2;
    const float* src; const float* W; const float* bias; float* dst; int r;
    if (row0 < NB * NQ) { r = row0;           src = queries + (size_t)r * DQK; W = W_q; bias = b_q; dst = eq; }
    else                { r = row0 - NB * NQ; src = keys    + (size_t)r * DQK; W = W_k; bias = b_k; dst = ek; }

    f32x2 a01A = {0.f, 0.f}, a23A = {0.f, 0.f};   // row r
    f32x2 a01B = {0.f, 0.f}, a23B = {0.f, 0.f};   // row r+1
    if (quarter == 0) {
        float4 bv4 = *(const float4*)(bias + h4);
        a01A = (f32x2){bv4.x, bv4.y}; a23A = (f32x2){bv4.z, bv4.w};
        a01B = a01A; a23B = a23A;
    }
    const float* srcA = src;
    const float* srcB = src + DQK;
    const int d0 = quarter * 64;
    #pragma unroll 4
    for (int i = d0; i < d0 + 64; i += 4) {
        float4 sA = *(const float4*)(srcA + i);
        float4 sB = *(const float4*)(srcB + i);
        float4 w0 = *(const float4*)(W + (size_t)(i + 0) * NH + h4);
        float4 w1 = *(const float4*)(W + (size_t)(i + 1) * NH + h4);
        float4 w2 = *(const float4*)(W + (size_t)(i + 2) * NH + h4);
        float4 w3 = *(const float4*)(W + (size_t)(i + 3) * NH + h4);
#define PSTEP2(SA, SB, WR) \
        a01A = __builtin_elementwise_fma((f32x2){SA, SA}, (f32x2){WR.x, WR.y}, a01A); \
        a23A = __builtin_elementwise_fma((f32x2){SA, SA}, (f32x2){WR.z, WR.w}, a23A); \
        a01B = __builtin_elementwise_fma((f32x2){SB, SB}, (f32x2){WR.x, WR.y}, a01B); \
        a23B = __builtin_elementwise_fma((f32x2){SB, SB}, (f32x2){WR.z, WR.w}, a23B);
        PSTEP2(sA.x, sB.x, w0) PSTEP2(sA.y, sB.y, w1)
        PSTEP2(sA.z, sB.z, w2) PSTEP2(sA.w, sB.w, w3)
#undef PSTEP2
    }
    float a0A = a01A.x, a1A = a01A.y, a2A = a23A.x, a3A = a23A.y;
    float a0B = a01B.x, a1B = a01B.y, a2B = a23B.x, a3B = a23B.y;
    a0A += __shfl_xor(a0A, 8, 64);  a1A += __shfl_xor(a1A, 8, 64);
    a2A += __shfl_xor(a2A, 8, 64);  a3A += __shfl_xor(a3A, 8, 64);
    a0B += __shfl_xor(a0B, 8, 64);  a1B += __shfl_xor(a1B, 8, 64);
    a2B += __shfl_xor(a2B, 8, 64);  a3B += __shfl_xor(a3B, 8, 64);
    a0A += __shfl_xor(a0A, 16, 64); a1A += __shfl_xor(a1A, 16, 64);
    a2A += __shfl_xor(a2A, 16, 64); a3A += __shfl_xor(a3A, 16, 64);
    a0B += __shfl_xor(a0B, 16, 64); a1B += __shfl_xor(a1B, 16, 64);
    a2B += __shfl_xor(a2B, 16, 64); a3B += __shfl_xor(a3B, 16, 64);
    if (quarter == 0) {
        float4 oA, oB;
        oA.x = __expf(2.f * a0A); oA.y = __expf(2.f * a1A);
        oA.z = __expf(2.f * a2A); oA.w = __expf(2.f * a3A);
        oB.x = __expf(2.f * a0B); oB.y = __expf(2.f * a1B);
        oB.z = __expf(2.f * a2B); oB.w = __expf(2.f * a3B);
        *(float4*)(dst + (size_t)r * NH + h4)       = oA;
        *(float4*)(dst + (size_t)(r + 1) * NH + h4) = oB;
    }
}

// ---------------------------------------------------------------------------
// Kernel 2: fused scores + softmax + weighted sum over values.
// Block = 512 threads (8 waves), handles (b, TQ=8 q-rows). grid = 4*128 = 512.
// Contiguous batch mapping (R3, measured best). Wave w owns k-range for BOTH
// score and BMM phases -> no inter-wave sync until the final reduction.
__global__ __launch_bounds__(BLK, 4) void attn_kernel(
    const float* __restrict__ eq, const float* __restrict__ ek,
    const float* __restrict__ values, const int* __restrict__ valid_lens,
    const float* __restrict__ w_v, float* __restrict__ out)
{
    __shared__ float s_w[NK][TQ];     // 32 KB: unnormalized exp-weights [k][q]; reused for partials
    __shared__ float s_part[8][TQ];   // per-wave softmax denominator partials

    const int t      = threadIdx.x;
    const int b      = blockIdx.x >> 7;
    const int q0     = (blockIdx.x & 127) * TQ;
    const int nvalid = valid_lens[b];           // [1, 1024]
    const int wave   = t >> 6;
    const int lane   = t & 63;
    const int qi     = lane & 7;
    const int kk     = lane >> 3;               // 0..7

    const int kpw  = (nvalid + 7) >> 3;
    const int kbeg = wave * kpw;
    const int kend = min(nvalid, kbeg + kpw);

    float wv[NH];
    #pragma unroll
    for (int h = 0; h < NH; h += 4) {
        float4 w4 = *(const float4*)(w_v + h);
        wv[h] = w4.x; wv[h+1] = w4.y; wv[h+2] = w4.z; wv[h+3] = w4.w;
    }
    float eqr[NH];
    const float* eqp = eq + (size_t)(b * NQ + q0 + qi) * NH;
    #pragma unroll
    for (int h = 0; h < NH; h += 4) {
        float4 e4 = *(const float4*)(eqp + h);
        eqr[h] = e4.x; eqr[h+1] = e4.y; eqr[h+2] = e4.z; eqr[h+3] = e4.w;
    }

    // ---- scores + exp -> unnormalized weights into this wave's s_w region
    const float* ekbase = ek + (size_t)b * NK * NH;
    float ssum = 0.f;
    for (int k0 = kbeg; k0 < kend; k0 += 8) {
        const int k = k0 + kk;
        if (k < kend) {
            const float* ekp = ekbase + (size_t)k * NH;
            float acc = 0.f;
            #pragma unroll
            for (int h = 0; h < NH; h += 4) {
                float4 e4 = *(const float4*)(ekp + h);
                float u0 = fmaf(eqr[h+0], e4.x, 1.f);
                float u1 = fmaf(eqr[h+1], e4.y, 1.f);
                float u2 = fmaf(eqr[h+2], e4.z, 1.f);
                float u3 = fmaf(eqr[h+3], e4.w, 1.f);
                float d01 = u0 * u1, d23 = u2 * u3;
                float n01 = fmaf(wv[h+0], u1, wv[h+1] * u0);
                float n23 = fmaf(wv[h+2], u3, wv[h+3] * u2);
                float d   = fminf(d01 * d23, 1e38f);   // inf guard
                float n   = fmaf(n01, d23, n23 * d01);
                acc = fmaf(n, fast_rcp(d), acc);
            }
            float e = __expf(-2.f * acc);
            s_w[k][qi] = e;          // lane mod 32 -> 2-way alias = free
            ssum += e;
        }
    }

    // per-wave softmax denominator partial (reduce over kk = lane bits 3..5)
    ssum += __shfl_xor(ssum, 8, 64);
    ssum += __shfl_xor(ssum, 16, 64);
    ssum += __shfl_xor(ssum, 32, 64);
    if (lane < TQ) s_part[wave][lane] = ssum;

    // ---- bmm over the same k-range (weights written by THIS wave: no barrier)
    // Packed fp32: 16 v_pk_fma_f32 per k instead of 32 v_fma_f32.
    f32x2 l0={0,0},h0={0,0}, l1={0,0},h1={0,0}, l2={0,0},h2={0,0}, l3={0,0},h3={0,0};
    f32x2 l4={0,0},h4={0,0}, l5={0,0},h5={0,0}, l6={0,0},h6={0,0}, l7={0,0},h7={0,0};
    const float* vbase = values + (size_t)b * NK * NV + 4 * lane;

#define PFMA(L, H, W) \
    L = __builtin_elementwise_fma((f32x2){W, W}, vl, L); \
    H = __builtin_elementwise_fma((f32x2){W, W}, vh, H);
    #pragma unroll 4
    for (int k = kbeg; k < kend; k++) {
        float4 v  = *(const float4*)(vbase + (size_t)k * NV);
        f32x2 vl = {v.x, v.y}, vh = {v.z, v.w};
        float4 w0 = *(const float4*)(&s_w[k][0]);   // wave-uniform broadcast
        float4 w1 = *(const float4*)(&s_w[k][4]);
        PFMA(l0, h0, w0.x) PFMA(l1, h1, w0.y) PFMA(l2, h2, w0.z) PFMA(l3, h3, w0.w)
        PFMA(l4, h4, w1.x) PFMA(l5, h5, w1.y) PFMA(l6, h6, w1.z) PFMA(l7, h7, w1.w)
    }
#undef PFMA
    float4 acc0 = {l0.x, l0.y, h0.x, h0.y}, acc1 = {l1.x, l1.y, h1.x, h1.y};
    float4 acc2 = {l2.x, l2.y, h2.x, h2.y}, acc3 = {l3.x, l3.y, h3.x, h3.y};
    float4 acc4 = {l4.x, l4.y, h4.x, h4.y}, acc5 = {l5.x, l5.y, h5.x, h5.y};
    float4 acc6 = {l6.x, l6.y, h6.x, h6.y}, acc7 = {l7.x, l7.y, h7.x, h7.y};

    __syncthreads();                 // everyone done with s_w as weights
    float* sred = &s_w[0][0];        // reuse 32 KB as [4 regions][q][256] partials
    float4* p = (float4*)(sred + (size_t)((wave & 3) * TQ) * 256) + lane;
    if (wave < 4) {                  // round A: waves 0..3 write their partials
        p[0*64] = acc0; p[1*64] = acc1; p[2*64] = acc2; p[3*64] = acc3;
        p[4*64] = acc4; p[5*64] = acc5; p[6*64] = acc6; p[7*64] = acc7;
    }
    __syncthreads();
    if (wave >= 4) {                 // round B: waves 4..7 accumulate in place
        float4 x4;
#define ACC4(I, A) x4 = p[I*64]; x4.x += A.x; x4.y += A.y; x4.z += A.z; x4.w += A.w; p[I*64] = x4;
        ACC4(0, acc0); ACC4(1, acc1); ACC4(2, acc2); ACC4(3, acc3);
        ACC4(4, acc4); ACC4(5, acc5); ACC4(6, acc6); ACC4(7, acc7);
#undef ACC4
    }
    __syncthreads();

    // ---- final reduction over 4 regions + deferred normalization.
    const int v  = t & 255;
    const int qh = (t >> 8) * 4;
    float* obase = out + (size_t)(b * NQ + q0) * NV + v;
    #pragma unroll
    for (int jj = 0; jj < 4; jj++) {
        const int q = qh + jj;
        float tot = 0.f;
        #pragma unroll
        for (int w = 0; w < 8; w++) tot += s_part[w][q];
        float rs = fast_rcp(tot);
        float r = sred[(0*TQ + q) * 256 + v] + sred[(1*TQ + q) * 256 + v]
                + sred[(2*TQ + q) * 256 + v] + sred[(3*TQ + q) * 256 + v];
        obase[(size_t)q * NV] = r * rs;
    }
}

// ---------------------------------------------------------------------------
extern "C" void kernel_launch(void* const* d_in, const int* in_sizes, int n_in,
                              void* d_out, int out_size, void* d_ws, size_t ws_size,
                              hipStream_t stream) {
    (void)in_sizes; (void)n_in; (void)out_size; (void)ws_size;
    const float* keys       = (const float*)d_in[0];
    const float* queries    = (const float*)d_in[1];
    const float* values     = (const float*)d_in[2];
    const int*   valid_lens = (const int*)d_in[3];
    const float* W_q        = (const float*)d_in[4];
    const float* b_q        = (const float*)d_in[5];
    const float* W_k        = (const float*)d_in[6];
    const float* b_k        = (const float*)d_in[7];
    const float* w_v        = (const float*)d_in[8];
    // d_in[9] = b_v: cancels in softmax.
    float* out = (float*)d_out;

    float* eq = (float*)d_ws;                       // B*Q*32 floats
    float* ek = eq + (size_t)NB * NQ * NH;          // B*K*32 floats

    proj_kernel<<<dim3(512), dim3(256), 0, stream>>>(queries, keys, W_q, b_q, W_k, b_k, eq, ek);
    attn_kernel<<<dim3(NB * (NQ / TQ)), dim3(BLK), 0, stream>>>(eq, ek, values, valid_lens, w_v, out);
}

// Round 6
// 105.827 us; speedup vs baseline: 1.0439x; 1.0139x over previous
//
#include <hip/hip_runtime.h>
#include <math.h>

// Additive attention, MI355X. B=4, Q=K=1024, QSIZE=KSIZE=256, H=32, VDIM=256.
//
// Math: tanh(fq+fk) = 1 - 2/(1 + e^{2fq} e^{2fk}); precompute eq=e^{2fq}, ek=e^{2fk}.
// score = const - 2*sum_h w_h/u_h, u_h = 1 + eq_h ek_h; const cancels in softmax.
// Rational 2-level combine -> 1 rcp per 4 h. Masked k skipped; normalization deferred.
//
// R14: R13/R9 structure EXACTLY, single change: attn block->(batch,q-group)
// decode is load-balance-aware. With 512 blocks round-robin over 256 CUs, CU c
// gets blocks (c, c+256); the old contiguous decode hard-wires batch pairs
// (0,2)/(1,3), so CU time ~ max(nv0+nv2, nv1+nv3). New decode sorts batches by
// valid_len (5-comparator network, wave-uniform, ~free) and assigns slots so
// each CU's two blocks are the OPTIMAL pairing (r0,r3)/(r1,r2). Same grid,
// same traffic, same 128-block same-batch contiguous runs (L2 locality kept).
// Per-q-row arithmetic unchanged -> absmax bit-identical.

#define NB 4
#define NQ 1024
#define NK 1024
#define DQK 256
#define NH 32
#define NV 256
#define TQ 8    // q-rows per attn block
#define BLK 512 // attn block size (8 waves)

typedef __attribute__((ext_vector_type(2))) float f32x2;

__device__ __forceinline__ float fast_rcp(float x) { return __builtin_amdgcn_rcpf(x); }

// ---------------------------------------------------------------------------
// Kernel 1: projections + exp(2x). Thread = (row-PAIR, 4-h group, quarter of dims).
// 4096 row-pairs * 8 hgroups * 4 quarters = 131072 threads = 512 blocks. (R9 exact)
__global__ __launch_bounds__(256) void proj_kernel(
    const float* __restrict__ queries, const float* __restrict__ keys,
    const float* __restrict__ W_q, const float* __restrict__ b_q,
    const float* __restrict__ W_k, const float* __restrict__ b_k,
    float* __restrict__ eq, float* __restrict__ ek)
{
    const int tid     = blockIdx.x * 256 + threadIdx.x;
    const int g       = tid >> 5;            // row-pair 0..4095
    const int sub     = tid & 31;
    const int h4      = (sub & 7) * 4;       // h-group
    const int quarter = sub >> 3;            // 0..3 -> dims quarter*64..+63

    const int row0 = g * 2;
    const float* src; const float* W; const float* bias; float* dst; int r;
    if (row0 < NB * NQ) { r = row0;           src = queries + (size_t)r * DQK; W = W_q; bias = b_q; dst = eq; }
    else                { r = row0 - NB * NQ; src = keys    + (size_t)r * DQK; W = W_k; bias = b_k; dst = ek; }

    f32x2 a01A = {0.f, 0.f}, a23A = {0.f, 0.f};   // row r
    f32x2 a01B = {0.f, 0.f}, a23B = {0.f, 0.f};   // row r+1
    if (quarter == 0) {
        float4 bv4 = *(const float4*)(bias + h4);
        a01A = (f32x2){bv4.x, bv4.y}; a23A = (f32x2){bv4.z, bv4.w};
        a01B = a01A; a23B = a23A;
    }
    const float* srcA = src;
    const float* srcB = src + DQK;
    const int d0 = quarter * 64;
    #pragma unroll 4
    for (int i = d0; i < d0 + 64; i += 4) {
        float4 sA = *(const float4*)(srcA + i);
        float4 sB = *(const float4*)(srcB + i);
        float4 w0 = *(const float4*)(W + (size_t)(i + 0) * NH + h4);
        float4 w1 = *(const float4*)(W + (size_t)(i + 1) * NH + h4);
        float4 w2 = *(const float4*)(W + (size_t)(i + 2) * NH + h4);
        float4 w3 = *(const float4*)(W + (size_t)(i + 3) * NH + h4);
#define PSTEP2(SA, SB, WR) \
        a01A = __builtin_elementwise_fma((f32x2){SA, SA}, (f32x2){WR.x, WR.y}, a01A); \
        a23A = __builtin_elementwise_fma((f32x2){SA, SA}, (f32x2){WR.z, WR.w}, a23A); \
        a01B = __builtin_elementwise_fma((f32x2){SB, SB}, (f32x2){WR.x, WR.y}, a01B); \
        a23B = __builtin_elementwise_fma((f32x2){SB, SB}, (f32x2){WR.z, WR.w}, a23B);
        PSTEP2(sA.x, sB.x, w0) PSTEP2(sA.y, sB.y, w1)
        PSTEP2(sA.z, sB.z, w2) PSTEP2(sA.w, sB.w, w3)
#undef PSTEP2
    }
    float a0A = a01A.x, a1A = a01A.y, a2A = a23A.x, a3A = a23A.y;
    float a0B = a01B.x, a1B = a01B.y, a2B = a23B.x, a3B = a23B.y;
    a0A += __shfl_xor(a0A, 8, 64);  a1A += __shfl_xor(a1A, 8, 64);
    a2A += __shfl_xor(a2A, 8, 64);  a3A += __shfl_xor(a3A, 8, 64);
    a0B += __shfl_xor(a0B, 8, 64);  a1B += __shfl_xor(a1B, 8, 64);
    a2B += __shfl_xor(a2B, 8, 64);  a3B += __shfl_xor(a3B, 8, 64);
    a0A += __shfl_xor(a0A, 16, 64); a1A += __shfl_xor(a1A, 16, 64);
    a2A += __shfl_xor(a2A, 16, 64); a3A += __shfl_xor(a3A, 16, 64);
    a0B += __shfl_xor(a0B, 16, 64); a1B += __shfl_xor(a1B, 16, 64);
    a2B += __shfl_xor(a2B, 16, 64); a3B += __shfl_xor(a3B, 16, 64);
    if (quarter == 0) {
        float4 oA, oB;
        oA.x = __expf(2.f * a0A); oA.y = __expf(2.f * a1A);
        oA.z = __expf(2.f * a2A); oA.w = __expf(2.f * a3A);
        oB.x = __expf(2.f * a0B); oB.y = __expf(2.f * a1B);
        oB.z = __expf(2.f * a2B); oB.w = __expf(2.f * a3B);
        *(float4*)(dst + (size_t)r * NH + h4)       = oA;
        *(float4*)(dst + (size_t)(r + 1) * NH + h4) = oB;
    }
}

// ---------------------------------------------------------------------------
// Kernel 2: fused scores + softmax + weighted sum over values.
// Block = 512 threads (8 waves), handles (b, TQ=8 q-rows). grid = 4*128 = 512.
// Load-balance-aware decode (R14); wave w owns k-range for BOTH score and BMM
// phases -> no inter-wave sync until the final reduction.
__global__ __launch_bounds__(BLK, 4) void attn_kernel(
    const float* __restrict__ eq, const float* __restrict__ ek,
    const float* __restrict__ values, const int* __restrict__ valid_lens,
    const float* __restrict__ w_v, float* __restrict__ out)
{
    __shared__ float s_w[NK][TQ];     // 32 KB: unnormalized exp-weights [k][q]; reused for partials
    __shared__ float s_part[8][TQ];   // per-wave softmax denominator partials

    const int t = threadIdx.x;

    // ---- balance-aware (batch, q-group) decode: identical in every block.
    // Sort batches by valid_len desc (deterministic strict-less network);
    // dispatch slots: j<128 -> pair (r0,r3), j>=128 -> pair (r1,r2);
    // g = bid>>8 picks the pair element, so CU c's blocks (c, c+256) get the
    // optimal-sum pairing. Contiguous 128-slot same-batch runs preserved.
    int nv0 = valid_lens[0], nv1 = valid_lens[1];
    int nv2 = valid_lens[2], nv3 = valid_lens[3];
    int i0 = 0, i1 = 1, i2 = 2, i3 = 3;
#define CS(NA, NB_, IA, IB) if (NA < NB_) { int tn = NA; NA = NB_; NB_ = tn; int ti = IA; IA = IB; IB = ti; }
    CS(nv0, nv1, i0, i1) CS(nv2, nv3, i2, i3)
    CS(nv0, nv2, i0, i2) CS(nv1, nv3, i1, i3)
    CS(nv1, nv2, i1, i2)
#undef CS
    const int j = blockIdx.x & 255;
    const int g = blockIdx.x >> 8;
    int b, nvalid, qg;
    if (j < 128) { b = g ? i3 : i0; nvalid = g ? nv3 : nv0; qg = j; }
    else         { b = g ? i2 : i1; nvalid = g ? nv2 : nv1; qg = j - 128; }
    const int q0 = qg * TQ;

    const int wave   = t >> 6;
    const int lane   = t & 63;
    const int qi     = lane & 7;
    const int kk     = lane >> 3;               // 0..7

    const int kpw  = (nvalid + 7) >> 3;
    const int kbeg = wave * kpw;
    const int kend = min(nvalid, kbeg + kpw);

    float wv[NH];
    #pragma unroll
    for (int h = 0; h < NH; h += 4) {
        float4 w4 = *(const float4*)(w_v + h);
        wv[h] = w4.x; wv[h+1] = w4.y; wv[h+2] = w4.z; wv[h+3] = w4.w;
    }
    float eqr[NH];
    const float* eqp = eq + (size_t)(b * NQ + q0 + qi) * NH;
    #pragma unroll
    for (int h = 0; h < NH; h += 4) {
        float4 e4 = *(const float4*)(eqp + h);
        eqr[h] = e4.x; eqr[h+1] = e4.y; eqr[h+2] = e4.z; eqr[h+3] = e4.w;
    }

    // ---- scores + exp -> unnormalized weights into this wave's s_w region
    const float* ekbase = ek + (size_t)b * NK * NH;
    float ssum = 0.f;
    for (int k0 = kbeg; k0 < kend; k0 += 8) {
        const int k = k0 + kk;
        if (k < kend) {
            const float* ekp = ekbase + (size_t)k * NH;
            float acc = 0.f;
            #pragma unroll
            for (int h = 0; h < NH; h += 4) {
                float4 e4 = *(const float4*)(ekp + h);
                float u0 = fmaf(eqr[h+0], e4.x, 1.f);
                float u1 = fmaf(eqr[h+1], e4.y, 1.f);
                float u2 = fmaf(eqr[h+2], e4.z, 1.f);
                float u3 = fmaf(eqr[h+3], e4.w, 1.f);
                float d01 = u0 * u1, d23 = u2 * u3;
                float n01 = fmaf(wv[h+0], u1, wv[h+1] * u0);
                float n23 = fmaf(wv[h+2], u3, wv[h+3] * u2);
                float d   = fminf(d01 * d23, 1e38f);   // inf guard
                float n   = fmaf(n01, d23, n23 * d01);
                acc = fmaf(n, fast_rcp(d), acc);
            }
            float e = __expf(-2.f * acc);
            s_w[k][qi] = e;          // lane mod 32 -> 2-way alias = free
            ssum += e;
        }
    }

    // per-wave softmax denominator partial (reduce over kk = lane bits 3..5)
    ssum += __shfl_xor(ssum, 8, 64);
    ssum += __shfl_xor(ssum, 16, 64);
    ssum += __shfl_xor(ssum, 32, 64);
    if (lane < TQ) s_part[wave][lane] = ssum;

    // ---- bmm over the same k-range (weights written by THIS wave: no barrier)
    // Packed fp32: 16 v_pk_fma_f32 per k instead of 32 v_fma_f32.
    f32x2 l0={0,0},h0={0,0}, l1={0,0},h1={0,0}, l2={0,0},h2={0,0}, l3={0,0},h3={0,0};
    f32x2 l4={0,0},h4={0,0}, l5={0,0},h5={0,0}, l6={0,0},h6={0,0}, l7={0,0},h7={0,0};
    const float* vbase = values + (size_t)b * NK * NV + 4 * lane;

#define PFMA(L, H, W) \
    L = __builtin_elementwise_fma((f32x2){W, W}, vl, L); \
    H = __builtin_elementwise_fma((f32x2){W, W}, vh, H);
    #pragma unroll 4
    for (int k = kbeg; k < kend; k++) {
        float4 v  = *(const float4*)(vbase + (size_t)k * NV);
        f32x2 vl = {v.x, v.y}, vh = {v.z, v.w};
        float4 w0 = *(const float4*)(&s_w[k][0]);   // wave-uniform broadcast
        float4 w1 = *(const float4*)(&s_w[k][4]);
        PFMA(l0, h0, w0.x) PFMA(l1, h1, w0.y) PFMA(l2, h2, w0.z) PFMA(l3, h3, w0.w)
        PFMA(l4, h4, w1.x) PFMA(l5, h5, w1.y) PFMA(l6, h6, w1.z) PFMA(l7, h7, w1.w)
    }
#undef PFMA
    float4 acc0 = {l0.x, l0.y, h0.x, h0.y}, acc1 = {l1.x, l1.y, h1.x, h1.y};
    float4 acc2 = {l2.x, l2.y, h2.x, h2.y}, acc3 = {l3.x, l3.y, h3.x, h3.y};
    float4 acc4 = {l4.x, l4.y, h4.x, h4.y}, acc5 = {l5.x, l5.y, h5.x, h5.y};
    float4 acc6 = {l6.x, l6.y, h6.x, h6.y}, acc7 = {l7.x, l7.y, h7.x, h7.y};

    __syncthreads();                 // everyone done with s_w as weights
    float* sred = &s_w[0][0];        // reuse 32 KB as [4 regions][q][256] partials
    float4* p = (float4*)(sred + (size_t)((wave & 3) * TQ) * 256) + lane;
    if (wave < 4) {                  // round A: waves 0..3 write their partials
        p[0*64] = acc0; p[1*64] = acc1; p[2*64] = acc2; p[3*64] = acc3;
        p[4*64] = acc4; p[5*64] = acc5; p[6*64] = acc6; p[7*64] = acc7;
    }
    __syncthreads();
    if (wave >= 4) {                 // round B: waves 4..7 accumulate in place
        float4 x4;
#define ACC4(I, A) x4 = p[I*64]; x4.x += A.x; x4.y += A.y; x4.z += A.z; x4.w += A.w; p[I*64] = x4;
        ACC4(0, acc0); ACC4(1, acc1); ACC4(2, acc2); ACC4(3, acc3);
        ACC4(4, acc4); ACC4(5, acc5); ACC4(6, acc6); ACC4(7, acc7);
#undef ACC4
    }
    __syncthreads();

    // ---- final reduction over 4 regions + deferred normalization.
    const int v  = t & 255;
    const int qh = (t >> 8) * 4;
    float* obase = out + (size_t)(b * NQ + q0) * NV + v;
    #pragma unroll
    for (int jj = 0; jj < 4; jj++) {
        const int q = qh + jj;
        float tot = 0.f;
        #pragma unroll
        for (int w = 0; w < 8; w++) tot += s_part[w][q];
        float rs = fast_rcp(tot);
        float r = sred[(0*TQ + q) * 256 + v] + sred[(1*TQ + q) * 256 + v]
                + sred[(2*TQ + q) * 256 + v] + sred[(3*TQ + q) * 256 + v];
        obase[(size_t)q * NV] = r * rs;
    }
}

// ---------------------------------------------------------------------------
extern "C" void kernel_launch(void* const* d_in, const int* in_sizes, int n_in,
                              void* d_out, int out_size, void* d_ws, size_t ws_size,
                              hipStream_t stream) {
    (void)in_sizes; (void)n_in; (void)out_size; (void)ws_size;
    const float* keys       = (const float*)d_in[0];
    const float* queries    = (const float*)d_in[1];
    const float* values     = (const float*)d_in[2];
    const int*   valid_lens = (const int*)d_in[3];
    const float* W_q        = (const float*)d_in[4];
    const float* b_q        = (const float*)d_in[5];
    const float* W_k        = (const float*)d_in[6];
    const float* b_k        = (const float*)d_in[7];
    const float* w_v        = (const float*)d_in[8];
    // d_in[9] = b_v: cancels in softmax.
    float* out = (float*)d_out;

    float* eq = (float*)d_ws;                       // B*Q*32 floats
    float* ek = eq + (size_t)NB * NQ * NH;          // B*K*32 floats

    proj_kernel<<<dim3(512), dim3(256), 0, stream>>>(queries, keys, W_q, b_q, W_k, b_k, eq, ek);
    attn_kernel<<<dim3(NB * (NQ / TQ)), dim3(BLK), 0, stream>>>(eq, ek, values, valid_lens, w_v, out);
}